// Round 6
// baseline (130.804 us; speedup 1.0000x reference)
//
#include <hip/hip_runtime.h>
#include <math.h>

#define HID 64
#define CH 4   // tiles (of 16 rows) per wave

typedef __attribute__((ext_vector_type(4))) float f32x4;
typedef __attribute__((ext_vector_type(8))) __bf16 bf16x8;

__device__ __forceinline__ float fast_tanh(float x) {
    // tanh(x) = 1 - 2/(exp(2x)+1); exp overflow -> inf -> rcp -> 0 -> 1 (correct)
    float e = __expf(2.0f * x);
    return 1.0f - 2.0f * __builtin_amdgcn_rcpf(e + 1.0f);
}

// ---- prep: bf16 weight tables (W2, W2^T) + E_des, all into d_ws ----
__global__ void prep_kernel(const float* __restrict__ W1, const float* __restrict__ b1,
                            const float* __restrict__ W2, const float* __restrict__ b2,
                            const float* __restrict__ W3, const float* __restrict__ b3,
                            const float* __restrict__ x0, float* __restrict__ edes_out,
                            __bf16* __restrict__ W2bf, __bf16* __restrict__ W2Tbf) {
    int tid = threadIdx.x;  // 256 threads
    for (int idx = tid; idx < HID * HID; idx += 256) {
        W2bf[idx] = (__bf16)W2[idx];
        int r = idx >> 6, c = idx & 63;
        W2Tbf[idx] = (__bf16)W2[c * HID + r];
    }
    if (tid < 64) {
        int j = tid;
        float q1 = x0[0], q2 = x0[1], p1 = x0[2], p2 = x0[3];
        float h1j = fast_tanh(fmaf(q1, W1[j], fmaf(q2, W1[HID + j], b1[j])));
        float z = b2[j];
#pragma unroll 1
        for (int i = 0; i < HID; i++) {
            float hi = __shfl(h1j, i, 64);
            z = fmaf(hi, W2[i * HID + j], z);
        }
        float h2 = fast_tanh(z);
        float v = h2 * W3[j];
#pragma unroll
        for (int off = 32; off; off >>= 1) v += __shfl_xor(v, off, 64);
        if (j == 0) {
            float V = v + b3[0];
            float s, c;
            __sincosf(q2, &s, &c);
            float DEN = 2.0f - c * c;
            float rDEN = __builtin_amdgcn_rcpf(DEN);
            float quad = (p1 * p1 - 2.0f * (c + 1.0f) * p1 * p2 + (2.0f * c + 3.0f) * p2 * p2) * rDEN;
            float kin = 0.5f * quad;
            float s1, c1;
            __sincosf(q1, &s1, &c1);
            float c12 = c1 * c - s1 * s;
            float dq = 1.57079632679489662f - q2;
            float pot = -9.81f * (c12 + 2.0f * c1) + 0.5f * dq * dq;
            edes_out[0] = pot + kin + V;
        }
    }
}

// ---- main: each wave does CH tiles of 16 rows; R4 body, per-chunk reloads, x prefetch ----
__global__ __launch_bounds__(256, 4) void pend_kernel(
    const float4* __restrict__ x,
    const float* __restrict__ W1, const float* __restrict__ b1,
    const __bf16* __restrict__ W2bf, const __bf16* __restrict__ W2Tbf,
    const float* __restrict__ b2,
    const float* __restrict__ W3, const float* __restrict__ b3,
    const float* __restrict__ Tp, const float* __restrict__ edes_p,
    float4* __restrict__ out, int n)
{
    __shared__ __align__(16) __bf16 lds[4 * 2048];  // per wave: h1[16][64], g2[16][64]
    const int tid = threadIdx.x;
    const int w = tid >> 6, l = tid & 63;
    const int lo = l & 15, hi = l >> 4;
    __bf16* h1buf = lds + w * 2048;
    __bf16* g2buf = h1buf + 1024;

    const float E_des = edes_p[0];
    const float Tabs = fabsf(Tp[0]);

    const int tile0 = (blockIdx.x * 4 + w) * CH;

    // prefetch x for chunk 0
    int epf = tile0 * 16 + lo;
    if (epf >= n) epf = n - 1;
    float4 xv_n = x[epf];

#pragma unroll 1
    for (int c = 0; c < CH; ++c) {
        const int tile = tile0 + c;
        const float4 xv = xv_n;
        if (c + 1 < CH) {
            int e2 = (tile + 1) * 16 + lo;
            if (e2 >= n) e2 = n - 1;
            xv_n = x[e2];                  // issued now, used next chunk
        }
        const float q1 = xv.x, q2 = xv.y, p1 = xv.z, p2 = xv.w;

        // ---- layer-1 in A-frag layout: lane holds (m=lo, k=32*kh+8*hi+t) ----
        bf16x8 a1[2];
#pragma unroll
        for (int kh = 0; kh < 2; kh++) {
            const int k0 = 32 * kh + 8 * hi;
            float wa[8], wb[8], bb[8];
            *(float4*)&wa[0] = *(const float4*)(W1 + k0);
            *(float4*)&wa[4] = *(const float4*)(W1 + k0 + 4);
            *(float4*)&wb[0] = *(const float4*)(W1 + HID + k0);
            *(float4*)&wb[4] = *(const float4*)(W1 + HID + k0 + 4);
            *(float4*)&bb[0] = *(const float4*)(b1 + k0);
            *(float4*)&bb[4] = *(const float4*)(b1 + k0 + 4);
#pragma unroll
            for (int t = 0; t < 8; t++) {
                float h = fast_tanh(fmaf(q1, wa[t], fmaf(q2, wb[t], bb[t])));
                a1[kh][t] = (__bf16)h;
            }
            const int idx = (lo * HID + k0) ^ ((lo & 7) << 3);
            *(bf16x8*)(h1buf + idx) = a1[kh];
        }

        // ---- GEMM1: Z2 = H1 @ W2 + b2 ----
        f32x4 accF[4];
#pragma unroll
        for (int nt = 0; nt < 4; nt++) {
            const float b2c = b2[16 * nt + lo];
            accF[nt] = (f32x4){b2c, b2c, b2c, b2c};
        }
#pragma unroll
        for (int nt = 0; nt < 4; nt++)
#pragma unroll
            for (int kh = 0; kh < 2; kh++) {
                const bf16x8 bfr = *(const bf16x8*)(W2Tbf + (16 * nt + lo) * HID + 32 * kh + 8 * hi);
                accF[nt] = __builtin_amdgcn_mfma_f32_16x16x32_bf16(a1[kh], bfr, accF[nt], 0, 0, 0);
            }

        // ---- h2 = tanh(z2); V partials; g2 = W3*(1-h2^2) -> LDS ----
        float vpart[4] = {0.f, 0.f, 0.f, 0.f};
#pragma unroll
        for (int nt = 0; nt < 4; nt++) {
            const int col = 16 * nt + lo;
            const float w3c = W3[col];
#pragma unroll
            for (int r = 0; r < 4; r++) {
                const float h2 = fast_tanh(accF[nt][r]);
                vpart[r] = fmaf(h2, w3c, vpart[r]);
                const float g = w3c * (1.0f - h2 * h2);
                const int row = 4 * hi + r;
                g2buf[(row * HID + col) ^ ((row & 7) << 3)] = (__bf16)g;
            }
        }

        // ---- GEMM2: R = G2 @ W2^T ----
        bf16x8 a2[2];
#pragma unroll
        for (int kh = 0; kh < 2; kh++) {
            const int idx = (lo * HID + 32 * kh + 8 * hi) ^ ((lo & 7) << 3);
            a2[kh] = *(const bf16x8*)(g2buf + idx);
        }
        f32x4 accB[4];
#pragma unroll
        for (int nt = 0; nt < 4; nt++) accB[nt] = (f32x4){0.f, 0.f, 0.f, 0.f};
#pragma unroll
        for (int nt = 0; nt < 4; nt++)
#pragma unroll
            for (int kh = 0; kh < 2; kh++) {
                const bf16x8 bfr = *(const bf16x8*)(W2bf + (16 * nt + lo) * HID + 32 * kh + 8 * hi);
                accB[nt] = __builtin_amdgcn_mfma_f32_16x16x32_bf16(a2[kh], bfr, accB[nt], 0, 0, 0);
            }

        // ---- gi = (1-h1^2)*R ; dVdq partials ----
        float d1part[4] = {0.f, 0.f, 0.f, 0.f}, d2part[4] = {0.f, 0.f, 0.f, 0.f};
#pragma unroll
        for (int nt = 0; nt < 4; nt++) {
            const int col = 16 * nt + lo;
            const float w1a = W1[col], w1b = W1[HID + col];
#pragma unroll
            for (int r = 0; r < 4; r++) {
                const int row = 4 * hi + r;
                const float h1v = (float)h1buf[(row * HID + col) ^ ((row & 7) << 3)];
                const float gi = (1.0f - h1v * h1v) * accB[nt][r];
                d1part[r] = fmaf(w1a, gi, d1part[r]);
                d2part[r] = fmaf(w1b, gi, d2part[r]);
            }
        }

        // ---- reduce over 16-lane col groups ----
#pragma unroll
        for (int r = 0; r < 4; r++)
#pragma unroll
            for (int off = 1; off < 16; off <<= 1) {
                vpart[r]  += __shfl_xor(vpart[r],  off, 64);
                d1part[r] += __shfl_xor(d1part[r], off, 64);
                d2part[r] += __shfl_xor(d2part[r], off, 64);
            }

        // ---- gather for row m = lo ----
        const int src = (lo >> 2) << 4;
        float tV[4], t1[4], t2[4];
#pragma unroll
        for (int r = 0; r < 4; r++) {
            tV[r] = __shfl(vpart[r],  src, 64);
            t1[r] = __shfl(d1part[r], src, 64);
            t2[r] = __shfl(d2part[r], src, 64);
        }
        const int rr = lo & 3;
        float V    = (rr == 0) ? tV[0] : (rr == 1) ? tV[1] : (rr == 2) ? tV[2] : tV[3];
        float dVq1 = (rr == 0) ? t1[0] : (rr == 1) ? t1[1] : (rr == 2) ? t1[2] : t1[3];
        float dVq2 = (rr == 0) ? t2[0] : (rr == 1) ? t2[1] : (rr == 2) ? t2[2] : t2[3];
        V += b3[0];

        // ---- physics (L1=L2=M1=M2=1, G=9.81, K1=0.5, A_E=1, B_DAMP=0) ----
        float s2q, c2q, s1q, c1q;
        __sincosf(q2, &s2q, &c2q);
        __sincosf(q1, &s1q, &c1q);
        float s12 = s1q * c2q + c1q * s2q;
        float c12 = c1q * c2q - s1q * s2q;

        float cc = c2q, s = s2q;
        float DEN = 2.0f - cc * cc;          // == 1 + s^2
        float rDEN = __builtin_amdgcn_rcpf(DEN);
        float cp1 = cc + 1.0f;

        float quad = (p1 * p1 - 2.0f * cp1 * p1 * p2 + (2.0f * cc + 3.0f) * p2 * p2) * rDEN;
        float kin = 0.5f * quad;
        float dqa = 1.57079632679489662f - q2;
        float pot = -9.81f * (c12 + 2.0f * c1q) + 0.5f * dqa * dqa;
        float E = pot + kin + V;

        float fac = (quad > 0.0f) ? __builtin_amdgcn_rsqf(quad) : 1.0f;
        float coef = E_des - E;
        float u1 = -dVq1 + coef * p1 * fac;
        float u2 = -dVq2 + coef * p2 * fac;

        float dq1dt = (p1 - cp1 * p2) * rDEN;
        float dq2dt = ((2.0f * cc + 3.0f) * p2 - cp1 * p1) * rDEN;
        float dp1dt = -9.81f * (s12 + 2.0f * s1q) + u1;

        float inner = -p2 * p2 * s * cp1 * (cc + 2.0f)
                    + p1 * p2 * s * (fmaf(cc, cc, fmaf(2.0f, cc, 2.0f)))
                    - cc * p1 * p1 * s
                    + DEN * DEN * (fmaf(9.81f, s12, -0.5f * (3.14159265358979324f - 2.0f * q2)));
        float dp2dt = -(inner * rDEN * rDEN) + u2;

        const int row = tile * 16 + lo;
        if (l < 16 && row < n) {
            float4 o;
            o.x = Tabs * dq1dt;
            o.y = Tabs * dq2dt;
            o.z = Tabs * dp1dt;
            o.w = Tabs * dp2dt;
            out[row] = o;
        }
    }
}

extern "C" void kernel_launch(void* const* d_in, const int* in_sizes, int n_in,
                              void* d_out, int out_size, void* d_ws, size_t ws_size,
                              hipStream_t stream) {
    const float* x  = (const float*)d_in[0];
    // d_in[1] = t (unused)
    const float* W1 = (const float*)d_in[2];
    const float* b1 = (const float*)d_in[3];
    const float* W2 = (const float*)d_in[4];
    const float* b2 = (const float*)d_in[5];
    const float* W3 = (const float*)d_in[6];
    const float* b3 = (const float*)d_in[7];
    const float* Tp = (const float*)d_in[8];
    const float* x0 = (const float*)d_in[9];

    float* ws = (float*)d_ws;
    float* edes = ws;                                   // 1 float (+ padding to 64B)
    __bf16* W2bf  = (__bf16*)(ws + 16);                 // 4096 bf16 = 8 KB
    __bf16* W2Tbf = W2bf + HID * HID;                   // 4096 bf16 = 8 KB

    prep_kernel<<<1, 256, 0, stream>>>(W1, b1, W2, b2, W3, b3, x0, edes, W2bf, W2Tbf);

    int n = in_sizes[0] / 4;  // 500000
    int tiles = (n + 15) / 16;                     // 31250
    int blocks = (tiles + 4 * CH - 1) / (4 * CH);  // 1954 blocks ~ 7.6/CU, one generation
    pend_kernel<<<blocks, 256, 0, stream>>>((const float4*)x, W1, b1, W2bf, W2Tbf,
                                            b2, W3, b3, Tp, edes, (float4*)d_out, n);
}

// Round 8
// 128.306 us; speedup vs baseline: 1.0195x; 1.0195x over previous
//
#include <hip/hip_runtime.h>
#include <math.h>

#define HID 64
#define CH 4   // tiles (of 16 rows) per wave

typedef __attribute__((ext_vector_type(4))) float f32x4;
typedef __attribute__((ext_vector_type(8))) __bf16 bf16x8;

__device__ __forceinline__ float fast_tanh(float x) {
    // tanh(x) = 1 - 2/(exp(2x)+1); exp overflow -> inf -> rcp -> 0 -> 1 (correct)
    float e = __expf(2.0f * x);
    return 1.0f - 2.0f * __builtin_amdgcn_rcpf(e + 1.0f);
}

// ---- prep: bf16 weight tables (W2, W2^T) + E_des, all into d_ws ----
__global__ void prep_kernel(const float* __restrict__ W1, const float* __restrict__ b1,
                            const float* __restrict__ W2, const float* __restrict__ b2,
                            const float* __restrict__ W3, const float* __restrict__ b3,
                            const float* __restrict__ x0, float* __restrict__ edes_out,
                            __bf16* __restrict__ W2bf, __bf16* __restrict__ W2Tbf) {
    int tid = threadIdx.x;  // 256 threads
    for (int idx = tid; idx < HID * HID; idx += 256) {
        W2bf[idx] = (__bf16)W2[idx];
        int r = idx >> 6, c = idx & 63;
        W2Tbf[idx] = (__bf16)W2[c * HID + r];
    }
    if (tid < 64) {
        int j = tid;
        float q1 = x0[0], q2 = x0[1], p1 = x0[2], p2 = x0[3];
        float h1j = fast_tanh(fmaf(q1, W1[j], fmaf(q2, W1[HID + j], b1[j])));
        float z = b2[j];
#pragma unroll 1
        for (int i = 0; i < HID; i++) {
            float hi = __shfl(h1j, i, 64);
            z = fmaf(hi, W2[i * HID + j], z);
        }
        float h2 = fast_tanh(z);
        float v = h2 * W3[j];
#pragma unroll
        for (int off = 32; off; off >>= 1) v += __shfl_xor(v, off, 64);
        if (j == 0) {
            float V = v + b3[0];
            float s, c;
            __sincosf(q2, &s, &c);
            float DEN = 2.0f - c * c;
            float rDEN = __builtin_amdgcn_rcpf(DEN);
            float quad = (p1 * p1 - 2.0f * (c + 1.0f) * p1 * p2 + (2.0f * c + 3.0f) * p2 * p2) * rDEN;
            float kin = 0.5f * quad;
            float s1, c1;
            __sincosf(q1, &s1, &c1);
            float c12 = c1 * c - s1 * s;
            float dq = 1.57079632679489662f - q2;
            float pot = -9.81f * (c12 + 2.0f * c1) + 0.5f * dq * dq;
            edes_out[0] = pot + kin + V;
        }
    }
}

// layer-1 half-fragment: 8 tanh from two float4 pairs, no local arrays
#define L1HALF(AFRAG, K0)                                                          \
    do {                                                                           \
        const float4 wa0 = *(const float4*)(W1 + (K0));                            \
        const float4 wa1 = *(const float4*)(W1 + (K0) + 4);                        \
        const float4 wb0 = *(const float4*)(W1 + HID + (K0));                      \
        const float4 wb1 = *(const float4*)(W1 + HID + (K0) + 4);                  \
        const float4 bb0 = *(const float4*)(b1 + (K0));                            \
        const float4 bb1 = *(const float4*)(b1 + (K0) + 4);                        \
        AFRAG[0] = (__bf16)fast_tanh(fmaf(q1, wa0.x, fmaf(q2, wb0.x, bb0.x)));     \
        AFRAG[1] = (__bf16)fast_tanh(fmaf(q1, wa0.y, fmaf(q2, wb0.y, bb0.y)));     \
        AFRAG[2] = (__bf16)fast_tanh(fmaf(q1, wa0.z, fmaf(q2, wb0.z, bb0.z)));     \
        AFRAG[3] = (__bf16)fast_tanh(fmaf(q1, wa0.w, fmaf(q2, wb0.w, bb0.w)));     \
        AFRAG[4] = (__bf16)fast_tanh(fmaf(q1, wa1.x, fmaf(q2, wb1.x, bb1.x)));     \
        AFRAG[5] = (__bf16)fast_tanh(fmaf(q1, wa1.y, fmaf(q2, wb1.y, bb1.y)));     \
        AFRAG[6] = (__bf16)fast_tanh(fmaf(q1, wa1.z, fmaf(q2, wb1.z, bb1.z)));     \
        AFRAG[7] = (__bf16)fast_tanh(fmaf(q1, wa1.w, fmaf(q2, wb1.w, bb1.w)));     \
    } while (0)

// h2/V/g2 block for one nt (ACC is a named f32x4)
#define H2BLOCK(ACC, NT)                                                                   \
    do {                                                                                   \
        const int col = 16 * (NT) + lo;                                                    \
        const float w3c = W3[col];                                                         \
        float h2, g; int row;                                                              \
        h2 = fast_tanh(ACC[0]); vp0 = fmaf(h2, w3c, vp0); g = w3c * (1.0f - h2 * h2);      \
        row = 4 * hi + 0; g2buf[(row * HID + col) ^ ((row & 7) << 3)] = (__bf16)g;         \
        h2 = fast_tanh(ACC[1]); vp1 = fmaf(h2, w3c, vp1); g = w3c * (1.0f - h2 * h2);      \
        row = 4 * hi + 1; g2buf[(row * HID + col) ^ ((row & 7) << 3)] = (__bf16)g;         \
        h2 = fast_tanh(ACC[2]); vp2 = fmaf(h2, w3c, vp2); g = w3c * (1.0f - h2 * h2);      \
        row = 4 * hi + 2; g2buf[(row * HID + col) ^ ((row & 7) << 3)] = (__bf16)g;         \
        h2 = fast_tanh(ACC[3]); vp3 = fmaf(h2, w3c, vp3); g = w3c * (1.0f - h2 * h2);      \
        row = 4 * hi + 3; g2buf[(row * HID + col) ^ ((row & 7) << 3)] = (__bf16)g;         \
    } while (0)

// backward dV block for one nt (ACC is a named f32x4)
#define DVBLOCK(ACC, NT)                                                                     \
    do {                                                                                     \
        const int col = 16 * (NT) + lo;                                                      \
        const float w1a = W1[col], w1b = W1[HID + col];                                      \
        float h1v, gi; int row;                                                              \
        row = 4 * hi + 0; h1v = (float)h1buf[(row * HID + col) ^ ((row & 7) << 3)];          \
        gi = (1.0f - h1v * h1v) * ACC[0]; d10 = fmaf(w1a, gi, d10); d20 = fmaf(w1b, gi, d20);\
        row = 4 * hi + 1; h1v = (float)h1buf[(row * HID + col) ^ ((row & 7) << 3)];          \
        gi = (1.0f - h1v * h1v) * ACC[1]; d11 = fmaf(w1a, gi, d11); d21 = fmaf(w1b, gi, d21);\
        row = 4 * hi + 2; h1v = (float)h1buf[(row * HID + col) ^ ((row & 7) << 3)];          \
        gi = (1.0f - h1v * h1v) * ACC[2]; d12 = fmaf(w1a, gi, d12); d22 = fmaf(w1b, gi, d22);\
        row = 4 * hi + 3; h1v = (float)h1buf[(row * HID + col) ^ ((row & 7) << 3)];          \
        gi = (1.0f - h1v * h1v) * ACC[3]; d13 = fmaf(w1a, gi, d13); d23 = fmaf(w1b, gi, d23);\
    } while (0)

// ---- main: each wave does CH tiles of 16 rows; NO local arrays in the loop ----
__global__ __launch_bounds__(256, 4) void pend_kernel(
    const float4* __restrict__ x,
    const float* __restrict__ W1, const float* __restrict__ b1,
    const __bf16* __restrict__ W2bf, const __bf16* __restrict__ W2Tbf,
    const float* __restrict__ b2,
    const float* __restrict__ W3, const float* __restrict__ b3,
    const float* __restrict__ Tp, const float* __restrict__ edes_p,
    float4* __restrict__ out, int n)
{
    __shared__ __align__(16) __bf16 lds[4 * 2048];  // per wave: h1[16][64], g2[16][64]
    const int tid = threadIdx.x;
    const int w = tid >> 6, l = tid & 63;
    const int lo = l & 15, hi = l >> 4;
    __bf16* h1buf = lds + w * 2048;
    __bf16* g2buf = h1buf + 1024;

    const float E_des = edes_p[0];
    const float Tabs = fabsf(Tp[0]);

    const int tile0 = (blockIdx.x * 4 + w) * CH;

    // prefetch x for chunk 0
    int epf = tile0 * 16 + lo;
    if (epf >= n) epf = n - 1;
    float4 xv_n = x[epf];

    // per-lane fragment bases (loop-invariant)
    const __bf16* w2t = W2Tbf + lo * HID + 8 * hi;  // + nt*1024 + kh*32
    const __bf16* w2b = W2bf  + lo * HID + 8 * hi;

    // A-fragment LDS indices (R4's exact formula, store == load)
    const int idxA = (lo * HID + 8 * hi)      ^ ((lo & 7) << 3);
    const int idxB = (lo * HID + 32 + 8 * hi) ^ ((lo & 7) << 3);

#pragma unroll 1
    for (int c = 0; c < CH; ++c) {
        const int tile = tile0 + c;
        const float4 xv = xv_n;
        if (c + 1 < CH) {
            int e2 = (tile + 1) * 16 + lo;
            if (e2 >= n) e2 = n - 1;
            xv_n = x[e2];                  // issued now, used next chunk
        }
        const float q1 = xv.x, q2 = xv.y, p1 = xv.z, p2 = xv.w;

        // ---- layer-1 in A-frag layout: lane holds (m=lo, k=32*kh+8*hi+t) ----
        bf16x8 a10, a11;
        L1HALF(a10, 8 * hi);
        L1HALF(a11, 32 + 8 * hi);
        *(bf16x8*)(h1buf + idxA) = a10;
        *(bf16x8*)(h1buf + idxB) = a11;

        // ---- GEMM1: Z2 = H1 @ W2 + b2 ----
        const float b2c0 = b2[lo], b2c1 = b2[16 + lo], b2c2 = b2[32 + lo], b2c3 = b2[48 + lo];
        f32x4 accF0 = {b2c0, b2c0, b2c0, b2c0};
        f32x4 accF1 = {b2c1, b2c1, b2c1, b2c1};
        f32x4 accF2 = {b2c2, b2c2, b2c2, b2c2};
        f32x4 accF3 = {b2c3, b2c3, b2c3, b2c3};
        accF0 = __builtin_amdgcn_mfma_f32_16x16x32_bf16(a10, *(const bf16x8*)(w2t + 0),    accF0, 0, 0, 0);
        accF0 = __builtin_amdgcn_mfma_f32_16x16x32_bf16(a11, *(const bf16x8*)(w2t + 32),   accF0, 0, 0, 0);
        accF1 = __builtin_amdgcn_mfma_f32_16x16x32_bf16(a10, *(const bf16x8*)(w2t + 1024), accF1, 0, 0, 0);
        accF1 = __builtin_amdgcn_mfma_f32_16x16x32_bf16(a11, *(const bf16x8*)(w2t + 1056), accF1, 0, 0, 0);
        accF2 = __builtin_amdgcn_mfma_f32_16x16x32_bf16(a10, *(const bf16x8*)(w2t + 2048), accF2, 0, 0, 0);
        accF2 = __builtin_amdgcn_mfma_f32_16x16x32_bf16(a11, *(const bf16x8*)(w2t + 2080), accF2, 0, 0, 0);
        accF3 = __builtin_amdgcn_mfma_f32_16x16x32_bf16(a10, *(const bf16x8*)(w2t + 3072), accF3, 0, 0, 0);
        accF3 = __builtin_amdgcn_mfma_f32_16x16x32_bf16(a11, *(const bf16x8*)(w2t + 3104), accF3, 0, 0, 0);

        // ---- h2 = tanh(z2); V partials; g2 = W3*(1-h2^2) -> LDS ----
        float vp0 = 0.f, vp1 = 0.f, vp2 = 0.f, vp3 = 0.f;
        H2BLOCK(accF0, 0);
        H2BLOCK(accF1, 1);
        H2BLOCK(accF2, 2);
        H2BLOCK(accF3, 3);

        // ---- GEMM2: R = G2 @ W2^T ----
        const bf16x8 a20 = *(const bf16x8*)(g2buf + idxA);
        const bf16x8 a21 = *(const bf16x8*)(g2buf + idxB);
        f32x4 accB0 = {0.f, 0.f, 0.f, 0.f};
        f32x4 accB1 = {0.f, 0.f, 0.f, 0.f};
        f32x4 accB2 = {0.f, 0.f, 0.f, 0.f};
        f32x4 accB3 = {0.f, 0.f, 0.f, 0.f};
        accB0 = __builtin_amdgcn_mfma_f32_16x16x32_bf16(a20, *(const bf16x8*)(w2b + 0),    accB0, 0, 0, 0);
        accB0 = __builtin_amdgcn_mfma_f32_16x16x32_bf16(a21, *(const bf16x8*)(w2b + 32),   accB0, 0, 0, 0);
        accB1 = __builtin_amdgcn_mfma_f32_16x16x32_bf16(a20, *(const bf16x8*)(w2b + 1024), accB1, 0, 0, 0);
        accB1 = __builtin_amdgcn_mfma_f32_16x16x32_bf16(a21, *(const bf16x8*)(w2b + 1056), accB1, 0, 0, 0);
        accB2 = __builtin_amdgcn_mfma_f32_16x16x32_bf16(a20, *(const bf16x8*)(w2b + 2048), accB2, 0, 0, 0);
        accB2 = __builtin_amdgcn_mfma_f32_16x16x32_bf16(a21, *(const bf16x8*)(w2b + 2080), accB2, 0, 0, 0);
        accB3 = __builtin_amdgcn_mfma_f32_16x16x32_bf16(a20, *(const bf16x8*)(w2b + 3072), accB3, 0, 0, 0);
        accB3 = __builtin_amdgcn_mfma_f32_16x16x32_bf16(a21, *(const bf16x8*)(w2b + 3104), accB3, 0, 0, 0);

        // ---- gi = (1-h1^2)*R ; dVdq partials ----
        float d10 = 0.f, d11 = 0.f, d12 = 0.f, d13 = 0.f;
        float d20 = 0.f, d21 = 0.f, d22 = 0.f, d23 = 0.f;
        DVBLOCK(accB0, 0);
        DVBLOCK(accB1, 1);
        DVBLOCK(accB2, 2);
        DVBLOCK(accB3, 3);

        // ---- reduce over 16-lane col groups ----
#pragma unroll
        for (int off = 1; off < 16; off <<= 1) {
            vp0 += __shfl_xor(vp0, off, 64);  vp1 += __shfl_xor(vp1, off, 64);
            vp2 += __shfl_xor(vp2, off, 64);  vp3 += __shfl_xor(vp3, off, 64);
            d10 += __shfl_xor(d10, off, 64);  d11 += __shfl_xor(d11, off, 64);
            d12 += __shfl_xor(d12, off, 64);  d13 += __shfl_xor(d13, off, 64);
            d20 += __shfl_xor(d20, off, 64);  d21 += __shfl_xor(d21, off, 64);
            d22 += __shfl_xor(d22, off, 64);  d23 += __shfl_xor(d23, off, 64);
        }

        // ---- gather for row m = lo (rows live in group hi = lo>>2) ----
        const int src = (lo >> 2) << 4;
        const float tV0 = __shfl(vp0, src, 64), tV1 = __shfl(vp1, src, 64);
        const float tV2 = __shfl(vp2, src, 64), tV3 = __shfl(vp3, src, 64);
        const float t10 = __shfl(d10, src, 64), t11 = __shfl(d11, src, 64);
        const float t12 = __shfl(d12, src, 64), t13 = __shfl(d13, src, 64);
        const float t20 = __shfl(d20, src, 64), t21 = __shfl(d21, src, 64);
        const float t22 = __shfl(d22, src, 64), t23 = __shfl(d23, src, 64);
        const int rr = lo & 3;
        float V    = (rr == 0) ? tV0 : (rr == 1) ? tV1 : (rr == 2) ? tV2 : tV3;
        float dVq1 = (rr == 0) ? t10 : (rr == 1) ? t11 : (rr == 2) ? t12 : t13;
        float dVq2 = (rr == 0) ? t20 : (rr == 1) ? t21 : (rr == 2) ? t22 : t23;
        V += b3[0];

        // ---- physics (L1=L2=M1=M2=1, G=9.81, K1=0.5, A_E=1, B_DAMP=0) ----
        float s2q, c2q, s1q, c1q;
        __sincosf(q2, &s2q, &c2q);
        __sincosf(q1, &s1q, &c1q);
        float s12 = s1q * c2q + c1q * s2q;
        float c12 = c1q * c2q - s1q * s2q;

        float cc = c2q, s = s2q;
        float DEN = 2.0f - cc * cc;          // == 1 + s^2
        float rDEN = __builtin_amdgcn_rcpf(DEN);
        float cp1 = cc + 1.0f;

        float quad = (p1 * p1 - 2.0f * cp1 * p1 * p2 + (2.0f * cc + 3.0f) * p2 * p2) * rDEN;
        float kin = 0.5f * quad;
        float dqa = 1.57079632679489662f - q2;
        float pot = -9.81f * (c12 + 2.0f * c1q) + 0.5f * dqa * dqa;
        float E = pot + kin + V;

        float fac = (quad > 0.0f) ? __builtin_amdgcn_rsqf(quad) : 1.0f;
        float coef = E_des - E;
        float u1 = -dVq1 + coef * p1 * fac;
        float u2 = -dVq2 + coef * p2 * fac;

        float dq1dt = (p1 - cp1 * p2) * rDEN;
        float dq2dt = ((2.0f * cc + 3.0f) * p2 - cp1 * p1) * rDEN;
        float dp1dt = -9.81f * (s12 + 2.0f * s1q) + u1;

        float inner = -p2 * p2 * s * cp1 * (cc + 2.0f)
                    + p1 * p2 * s * (fmaf(cc, cc, fmaf(2.0f, cc, 2.0f)))
                    - cc * p1 * p1 * s
                    + DEN * DEN * (fmaf(9.81f, s12, -0.5f * (3.14159265358979324f - 2.0f * q2)));
        float dp2dt = -(inner * rDEN * rDEN) + u2;

        const int row = tile * 16 + lo;
        if (l < 16 && row < n) {
            float4 o;
            o.x = Tabs * dq1dt;
            o.y = Tabs * dq2dt;
            o.z = Tabs * dp1dt;
            o.w = Tabs * dp2dt;
            out[row] = o;
        }
    }
}

extern "C" void kernel_launch(void* const* d_in, const int* in_sizes, int n_in,
                              void* d_out, int out_size, void* d_ws, size_t ws_size,
                              hipStream_t stream) {
    const float* x  = (const float*)d_in[0];
    // d_in[1] = t (unused)
    const float* W1 = (const float*)d_in[2];
    const float* b1 = (const float*)d_in[3];
    const float* W2 = (const float*)d_in[4];
    const float* b2 = (const float*)d_in[5];
    const float* W3 = (const float*)d_in[6];
    const float* b3 = (const float*)d_in[7];
    const float* Tp = (const float*)d_in[8];
    const float* x0 = (const float*)d_in[9];

    float* ws = (float*)d_ws;
    float* edes = ws;                                   // 1 float (+ padding to 64B)
    __bf16* W2bf  = (__bf16*)(ws + 16);                 // 4096 bf16 = 8 KB
    __bf16* W2Tbf = W2bf + HID * HID;                   // 4096 bf16 = 8 KB

    prep_kernel<<<1, 256, 0, stream>>>(W1, b1, W2, b2, W3, b3, x0, edes, W2bf, W2Tbf);

    int n = in_sizes[0] / 4;  // 500000
    int tiles = (n + 15) / 16;                     // 31250
    int blocks = (tiles + 4 * CH - 1) / (4 * CH);  // 1954 blocks ~ 7.6/CU, one generation
    pend_kernel<<<blocks, 256, 0, stream>>>((const float4*)x, W1, b1, W2bf, W2Tbf,
                                            b2, W3, b3, Tp, edes, (float4*)d_out, n);
}

// Round 9
// 86.277 us; speedup vs baseline: 1.5161x; 1.4871x over previous
//
#include <hip/hip_runtime.h>
#include <math.h>

#define HID 64

typedef __attribute__((ext_vector_type(4))) float f32x4;
typedef __attribute__((ext_vector_type(8))) __bf16 bf16x8;

__device__ __forceinline__ float fast_tanh(float x) {
    // tanh(x) = 1 - 2/(exp(2x)+1); exp overflow -> inf -> rcp -> 0 -> 1 (correct)
    float e = __expf(2.0f * x);
    return 1.0f - 2.0f * __builtin_amdgcn_rcpf(e + 1.0f);
}

// ---- prep: bf16 weight tables (W2, W2^T) + E_des, all into d_ws ----
__global__ void prep_kernel(const float* __restrict__ W1, const float* __restrict__ b1,
                            const float* __restrict__ W2, const float* __restrict__ b2,
                            const float* __restrict__ W3, const float* __restrict__ b3,
                            const float* __restrict__ x0, float* __restrict__ edes_out,
                            __bf16* __restrict__ W2bf, __bf16* __restrict__ W2Tbf) {
    int tid = threadIdx.x;  // 256 threads
    for (int idx = tid; idx < HID * HID; idx += 256) {
        W2bf[idx] = (__bf16)W2[idx];
        int r = idx >> 6, c = idx & 63;
        W2Tbf[idx] = (__bf16)W2[c * HID + r];
    }
    if (tid < 64) {
        int j = tid;
        float q1 = x0[0], q2 = x0[1], p1 = x0[2], p2 = x0[3];
        float h1j = fast_tanh(fmaf(q1, W1[j], fmaf(q2, W1[HID + j], b1[j])));
        float z = b2[j];
#pragma unroll 1
        for (int i = 0; i < HID; i++) {
            float hi = __shfl(h1j, i, 64);
            z = fmaf(hi, W2[i * HID + j], z);
        }
        float h2 = fast_tanh(z);
        float v = h2 * W3[j];
#pragma unroll
        for (int off = 32; off; off >>= 1) v += __shfl_xor(v, off, 64);
        if (j == 0) {
            float V = v + b3[0];
            float s, c;
            __sincosf(q2, &s, &c);
            float DEN = 2.0f - c * c;
            float rDEN = __builtin_amdgcn_rcpf(DEN);
            float quad = (p1 * p1 - 2.0f * (c + 1.0f) * p1 * p2 + (2.0f * c + 3.0f) * p2 * p2) * rDEN;
            float kin = 0.5f * quad;
            float s1, c1;
            __sincosf(q1, &s1, &c1);
            float c12 = c1 * c - s1 * s;
            float dq = 1.57079632679489662f - q2;
            float pot = -9.81f * (c12 + 2.0f * c1) + 0.5f * dq * dq;
            edes_out[0] = pot + kin + V;
        }
    }
}

// layer-1 half-fragment: 8 tanh from two float4 pairs, no local arrays
#define L1HALF(AFRAG, K0)                                                          \
    do {                                                                           \
        const float4 wa0 = *(const float4*)(W1 + (K0));                            \
        const float4 wa1 = *(const float4*)(W1 + (K0) + 4);                        \
        const float4 wb0 = *(const float4*)(W1 + HID + (K0));                      \
        const float4 wb1 = *(const float4*)(W1 + HID + (K0) + 4);                  \
        const float4 bb0 = *(const float4*)(b1 + (K0));                            \
        const float4 bb1 = *(const float4*)(b1 + (K0) + 4);                        \
        AFRAG[0] = (__bf16)fast_tanh(fmaf(q1, wa0.x, fmaf(q2, wb0.x, bb0.x)));     \
        AFRAG[1] = (__bf16)fast_tanh(fmaf(q1, wa0.y, fmaf(q2, wb0.y, bb0.y)));     \
        AFRAG[2] = (__bf16)fast_tanh(fmaf(q1, wa0.z, fmaf(q2, wb0.z, bb0.z)));     \
        AFRAG[3] = (__bf16)fast_tanh(fmaf(q1, wa0.w, fmaf(q2, wb0.w, bb0.w)));     \
        AFRAG[4] = (__bf16)fast_tanh(fmaf(q1, wa1.x, fmaf(q2, wb1.x, bb1.x)));     \
        AFRAG[5] = (__bf16)fast_tanh(fmaf(q1, wa1.y, fmaf(q2, wb1.y, bb1.y)));     \
        AFRAG[6] = (__bf16)fast_tanh(fmaf(q1, wa1.z, fmaf(q2, wb1.z, bb1.z)));     \
        AFRAG[7] = (__bf16)fast_tanh(fmaf(q1, wa1.w, fmaf(q2, wb1.w, bb1.w)));     \
    } while (0)

// h2/V/g2 block for one nt (ACC is a named f32x4)
#define H2BLOCK(ACC, NT)                                                                   \
    do {                                                                                   \
        const int col = 16 * (NT) + lo;                                                    \
        const float w3c = W3[col];                                                         \
        float h2, g; int row;                                                              \
        h2 = fast_tanh(ACC[0]); vp0 = fmaf(h2, w3c, vp0); g = w3c * (1.0f - h2 * h2);      \
        row = 4 * hi + 0; g2buf[(row * HID + col) ^ ((row & 7) << 3)] = (__bf16)g;         \
        h2 = fast_tanh(ACC[1]); vp1 = fmaf(h2, w3c, vp1); g = w3c * (1.0f - h2 * h2);      \
        row = 4 * hi + 1; g2buf[(row * HID + col) ^ ((row & 7) << 3)] = (__bf16)g;         \
        h2 = fast_tanh(ACC[2]); vp2 = fmaf(h2, w3c, vp2); g = w3c * (1.0f - h2 * h2);      \
        row = 4 * hi + 2; g2buf[(row * HID + col) ^ ((row & 7) << 3)] = (__bf16)g;         \
        h2 = fast_tanh(ACC[3]); vp3 = fmaf(h2, w3c, vp3); g = w3c * (1.0f - h2 * h2);      \
        row = 4 * hi + 3; g2buf[(row * HID + col) ^ ((row & 7) << 3)] = (__bf16)g;         \
    } while (0)

// backward dV block for one nt (ACC is a named f32x4)
#define DVBLOCK(ACC, NT)                                                                     \
    do {                                                                                     \
        const int col = 16 * (NT) + lo;                                                      \
        const float w1a = W1[col], w1b = W1[HID + col];                                      \
        float h1v, gi; int row;                                                              \
        row = 4 * hi + 0; h1v = (float)h1buf[(row * HID + col) ^ ((row & 7) << 3)];          \
        gi = (1.0f - h1v * h1v) * ACC[0]; d10 = fmaf(w1a, gi, d10); d20 = fmaf(w1b, gi, d20);\
        row = 4 * hi + 1; h1v = (float)h1buf[(row * HID + col) ^ ((row & 7) << 3)];          \
        gi = (1.0f - h1v * h1v) * ACC[1]; d11 = fmaf(w1a, gi, d11); d21 = fmaf(w1b, gi, d21);\
        row = 4 * hi + 2; h1v = (float)h1buf[(row * HID + col) ^ ((row & 7) << 3)];          \
        gi = (1.0f - h1v * h1v) * ACC[2]; d12 = fmaf(w1a, gi, d12); d22 = fmaf(w1b, gi, d22);\
        row = 4 * hi + 3; h1v = (float)h1buf[(row * HID + col) ^ ((row & 7) << 3)];          \
        gi = (1.0f - h1v * h1v) * ACC[3]; d13 = fmaf(w1a, gi, d13); d23 = fmaf(w1b, gi, d23);\
    } while (0)

// ---- main: each wave does 4 consecutive tiles, STRAIGHT-LINE (inlined 4x, no loop) ----
__global__ __launch_bounds__(256, 4) void pend_kernel(
    const float4* __restrict__ x,
    const float* __restrict__ W1, const float* __restrict__ b1,
    const __bf16* __restrict__ W2bf, const __bf16* __restrict__ W2Tbf,
    const float* __restrict__ b2,
    const float* __restrict__ W3, const float* __restrict__ b3,
    const float* __restrict__ Tp, const float* __restrict__ edes_p,
    float4* __restrict__ out, int n)
{
    __shared__ __align__(16) __bf16 lds[4 * 2048];  // per wave: h1[16][64], g2[16][64]
    const int tid = threadIdx.x;
    const int w = tid >> 6, l = tid & 63;
    const int lo = l & 15, hi = l >> 4;
    __bf16* h1buf = lds + w * 2048;
    __bf16* g2buf = h1buf + 1024;

    const float E_des = edes_p[0];
    const float Tabs = fabsf(Tp[0]);

    // per-lane fragment bases (invariant)
    const __bf16* w2t = W2Tbf + lo * HID + 8 * hi;  // + nt*1024 + kh*32
    const __bf16* w2b = W2bf  + lo * HID + 8 * hi;

    // A-fragment LDS indices (store == load, R4's verified formula)
    const int idxA = (lo * HID + 8 * hi)      ^ ((lo & 7) << 3);
    const int idxB = (lo * HID + 32 + 8 * hi) ^ ((lo & 7) << 3);

    const int base_t = (blockIdx.x * 4 + w) * 4;   // first of 4 consecutive tiles

    // issue all 4 x loads up-front (independent; later ones hide under compute)
    int e0 = base_t * 16 + lo;          if (e0 >= n) e0 = n - 1;
    int e1 = (base_t + 1) * 16 + lo;    if (e1 >= n) e1 = n - 1;
    int e2 = (base_t + 2) * 16 + lo;    if (e2 >= n) e2 = n - 1;
    int e3 = (base_t + 3) * 16 + lo;    if (e3 >= n) e3 = n - 1;
    const float4 xv0 = x[e0];
    const float4 xv1 = x[e1];
    const float4 xv2 = x[e2];
    const float4 xv3 = x[e3];

    auto doTile = [&](int tile, float4 xv) {
        const float q1 = xv.x, q2 = xv.y, p1 = xv.z, p2 = xv.w;

        // ---- layer-1 in A-frag layout: lane holds (m=lo, k=32*kh+8*hi+t) ----
        bf16x8 a10, a11;
        L1HALF(a10, 8 * hi);
        L1HALF(a11, 32 + 8 * hi);
        *(bf16x8*)(h1buf + idxA) = a10;
        *(bf16x8*)(h1buf + idxB) = a11;

        // ---- GEMM1: Z2 = H1 @ W2 + b2 ----
        const float b2c0 = b2[lo], b2c1 = b2[16 + lo], b2c2 = b2[32 + lo], b2c3 = b2[48 + lo];
        f32x4 accF0 = {b2c0, b2c0, b2c0, b2c0};
        f32x4 accF1 = {b2c1, b2c1, b2c1, b2c1};
        f32x4 accF2 = {b2c2, b2c2, b2c2, b2c2};
        f32x4 accF3 = {b2c3, b2c3, b2c3, b2c3};
        accF0 = __builtin_amdgcn_mfma_f32_16x16x32_bf16(a10, *(const bf16x8*)(w2t + 0),    accF0, 0, 0, 0);
        accF0 = __builtin_amdgcn_mfma_f32_16x16x32_bf16(a11, *(const bf16x8*)(w2t + 32),   accF0, 0, 0, 0);
        accF1 = __builtin_amdgcn_mfma_f32_16x16x32_bf16(a10, *(const bf16x8*)(w2t + 1024), accF1, 0, 0, 0);
        accF1 = __builtin_amdgcn_mfma_f32_16x16x32_bf16(a11, *(const bf16x8*)(w2t + 1056), accF1, 0, 0, 0);
        accF2 = __builtin_amdgcn_mfma_f32_16x16x32_bf16(a10, *(const bf16x8*)(w2t + 2048), accF2, 0, 0, 0);
        accF2 = __builtin_amdgcn_mfma_f32_16x16x32_bf16(a11, *(const bf16x8*)(w2t + 2080), accF2, 0, 0, 0);
        accF3 = __builtin_amdgcn_mfma_f32_16x16x32_bf16(a10, *(const bf16x8*)(w2t + 3072), accF3, 0, 0, 0);
        accF3 = __builtin_amdgcn_mfma_f32_16x16x32_bf16(a11, *(const bf16x8*)(w2t + 3104), accF3, 0, 0, 0);

        // ---- h2 = tanh(z2); V partials; g2 = W3*(1-h2^2) -> LDS ----
        float vp0 = 0.f, vp1 = 0.f, vp2 = 0.f, vp3 = 0.f;
        H2BLOCK(accF0, 0);
        H2BLOCK(accF1, 1);
        H2BLOCK(accF2, 2);
        H2BLOCK(accF3, 3);

        // ---- GEMM2: R = G2 @ W2^T ----
        const bf16x8 a20 = *(const bf16x8*)(g2buf + idxA);
        const bf16x8 a21 = *(const bf16x8*)(g2buf + idxB);
        f32x4 accB0 = {0.f, 0.f, 0.f, 0.f};
        f32x4 accB1 = {0.f, 0.f, 0.f, 0.f};
        f32x4 accB2 = {0.f, 0.f, 0.f, 0.f};
        f32x4 accB3 = {0.f, 0.f, 0.f, 0.f};
        accB0 = __builtin_amdgcn_mfma_f32_16x16x32_bf16(a20, *(const bf16x8*)(w2b + 0),    accB0, 0, 0, 0);
        accB0 = __builtin_amdgcn_mfma_f32_16x16x32_bf16(a21, *(const bf16x8*)(w2b + 32),   accB0, 0, 0, 0);
        accB1 = __builtin_amdgcn_mfma_f32_16x16x32_bf16(a20, *(const bf16x8*)(w2b + 1024), accB1, 0, 0, 0);
        accB1 = __builtin_amdgcn_mfma_f32_16x16x32_bf16(a21, *(const bf16x8*)(w2b + 1056), accB1, 0, 0, 0);
        accB2 = __builtin_amdgcn_mfma_f32_16x16x32_bf16(a20, *(const bf16x8*)(w2b + 2048), accB2, 0, 0, 0);
        accB2 = __builtin_amdgcn_mfma_f32_16x16x32_bf16(a21, *(const bf16x8*)(w2b + 2080), accB2, 0, 0, 0);
        accB3 = __builtin_amdgcn_mfma_f32_16x16x32_bf16(a20, *(const bf16x8*)(w2b + 3072), accB3, 0, 0, 0);
        accB3 = __builtin_amdgcn_mfma_f32_16x16x32_bf16(a21, *(const bf16x8*)(w2b + 3104), accB3, 0, 0, 0);

        // ---- gi = (1-h1^2)*R ; dVdq partials ----
        float d10 = 0.f, d11 = 0.f, d12 = 0.f, d13 = 0.f;
        float d20 = 0.f, d21 = 0.f, d22 = 0.f, d23 = 0.f;
        DVBLOCK(accB0, 0);
        DVBLOCK(accB1, 1);
        DVBLOCK(accB2, 2);
        DVBLOCK(accB3, 3);

        // ---- reduce over 16-lane col groups ----
#pragma unroll
        for (int off = 1; off < 16; off <<= 1) {
            vp0 += __shfl_xor(vp0, off, 64);  vp1 += __shfl_xor(vp1, off, 64);
            vp2 += __shfl_xor(vp2, off, 64);  vp3 += __shfl_xor(vp3, off, 64);
            d10 += __shfl_xor(d10, off, 64);  d11 += __shfl_xor(d11, off, 64);
            d12 += __shfl_xor(d12, off, 64);  d13 += __shfl_xor(d13, off, 64);
            d20 += __shfl_xor(d20, off, 64);  d21 += __shfl_xor(d21, off, 64);
            d22 += __shfl_xor(d22, off, 64);  d23 += __shfl_xor(d23, off, 64);
        }

        // ---- gather for row m = lo (rows live in group hi = lo>>2) ----
        const int src = (lo >> 2) << 4;
        const float tV0 = __shfl(vp0, src, 64), tV1 = __shfl(vp1, src, 64);
        const float tV2 = __shfl(vp2, src, 64), tV3 = __shfl(vp3, src, 64);
        const float t10 = __shfl(d10, src, 64), t11 = __shfl(d11, src, 64);
        const float t12 = __shfl(d12, src, 64), t13 = __shfl(d13, src, 64);
        const float t20 = __shfl(d20, src, 64), t21 = __shfl(d21, src, 64);
        const float t22 = __shfl(d22, src, 64), t23 = __shfl(d23, src, 64);
        const int rr = lo & 3;
        float V    = (rr == 0) ? tV0 : (rr == 1) ? tV1 : (rr == 2) ? tV2 : tV3;
        float dVq1 = (rr == 0) ? t10 : (rr == 1) ? t11 : (rr == 2) ? t12 : t13;
        float dVq2 = (rr == 0) ? t20 : (rr == 1) ? t21 : (rr == 2) ? t22 : t23;
        V += b3[0];

        // ---- physics (L1=L2=M1=M2=1, G=9.81, K1=0.5, A_E=1, B_DAMP=0) ----
        float s2q, c2q, s1q, c1q;
        __sincosf(q2, &s2q, &c2q);
        __sincosf(q1, &s1q, &c1q);
        float s12 = s1q * c2q + c1q * s2q;
        float c12 = c1q * c2q - s1q * s2q;

        float cc = c2q, s = s2q;
        float DEN = 2.0f - cc * cc;          // == 1 + s^2
        float rDEN = __builtin_amdgcn_rcpf(DEN);
        float cp1 = cc + 1.0f;

        float quad = (p1 * p1 - 2.0f * cp1 * p1 * p2 + (2.0f * cc + 3.0f) * p2 * p2) * rDEN;
        float kin = 0.5f * quad;
        float dqa = 1.57079632679489662f - q2;
        float pot = -9.81f * (c12 + 2.0f * c1q) + 0.5f * dqa * dqa;
        float E = pot + kin + V;

        float fac = (quad > 0.0f) ? __builtin_amdgcn_rsqf(quad) : 1.0f;
        float coef = E_des - E;
        float u1 = -dVq1 + coef * p1 * fac;
        float u2 = -dVq2 + coef * p2 * fac;

        float dq1dt = (p1 - cp1 * p2) * rDEN;
        float dq2dt = ((2.0f * cc + 3.0f) * p2 - cp1 * p1) * rDEN;
        float dp1dt = -9.81f * (s12 + 2.0f * s1q) + u1;

        float inner = -p2 * p2 * s * cp1 * (cc + 2.0f)
                    + p1 * p2 * s * (fmaf(cc, cc, fmaf(2.0f, cc, 2.0f)))
                    - cc * p1 * p1 * s
                    + DEN * DEN * (fmaf(9.81f, s12, -0.5f * (3.14159265358979324f - 2.0f * q2)));
        float dp2dt = -(inner * rDEN * rDEN) + u2;

        const int row = tile * 16 + lo;
        if (l < 16 && row < n) {
            float4 o;
            o.x = Tabs * dq1dt;
            o.y = Tabs * dq2dt;
            o.z = Tabs * dp1dt;
            o.w = Tabs * dp2dt;
            out[row] = o;
        }
    };

    doTile(base_t + 0, xv0);
    doTile(base_t + 1, xv1);
    doTile(base_t + 2, xv2);
    doTile(base_t + 3, xv3);
}

extern "C" void kernel_launch(void* const* d_in, const int* in_sizes, int n_in,
                              void* d_out, int out_size, void* d_ws, size_t ws_size,
                              hipStream_t stream) {
    const float* x  = (const float*)d_in[0];
    // d_in[1] = t (unused)
    const float* W1 = (const float*)d_in[2];
    const float* b1 = (const float*)d_in[3];
    const float* W2 = (const float*)d_in[4];
    const float* b2 = (const float*)d_in[5];
    const float* W3 = (const float*)d_in[6];
    const float* b3 = (const float*)d_in[7];
    const float* Tp = (const float*)d_in[8];
    const float* x0 = (const float*)d_in[9];

    float* ws = (float*)d_ws;
    float* edes = ws;                                   // 1 float (+ padding to 64B)
    __bf16* W2bf  = (__bf16*)(ws + 16);                 // 4096 bf16 = 8 KB
    __bf16* W2Tbf = W2bf + HID * HID;                   // 4096 bf16 = 8 KB

    prep_kernel<<<1, 256, 0, stream>>>(W1, b1, W2, b2, W3, b3, x0, edes, W2bf, W2Tbf);

    int n = in_sizes[0] / 4;  // 500000
    int tiles = (n + 15) / 16;                     // 31250
    int blocks = (tiles + 15) / 16;                // 4 waves x 4 tiles per block -> 1954
    pend_kernel<<<blocks, 256, 0, stream>>>((const float4*)x, W1, b1, W2bf, W2Tbf,
                                            b2, W3, b3, Tp, edes, (float4*)d_out, n);
}